// Round 10
// baseline (272.998 us; speedup 1.0000x reference)
//
#include <hip/hip_runtime.h>

#define N_NODES 100000
#define N_EDGES 1600000
constexpr int BLK = 256;
constexpr int NBKT = (N_NODES + 127) / 128;   // 782 buckets of 128 nodes
constexpr int PACK_SHIFT = 17;                // src < 2^17
constexpr int EPT = 16;                       // edges/thread in scatter
constexpr int EPBLK = BLK * EPT;              // 4096
constexpr int NSCAT = (N_EDGES + EPBLK - 1) / EPBLK;   // 391

// ---------- bf16 helpers (RTNE) ----------
__device__ __forceinline__ unsigned short f2bf(float f) {
    unsigned int u = __float_as_uint(f);
    u = (u + 0x7FFFu + ((u >> 16) & 1u)) >> 16;
    return (unsigned short)u;
}
__device__ __forceinline__ float bf2f(unsigned short s) {
    return __uint_as_float(((unsigned int)s) << 16);
}

// ---------- edge dtype detection (int32 vs int64-lowword) ----------
__global__ void detect_idx64(const unsigned int* __restrict__ e, int* __restrict__ flag) {
    if (blockIdx.x == 0 && threadIdx.x == 0) {
        int is64 = 1;
        for (int i = 0; i < 64; ++i) if (e[2 * i + 1] != 0u) { is64 = 0; break; }
        *flag = is64;
    }
}

__device__ __forceinline__ int load_dst(const int* e, int f, int i) {
    return f ? e[2 * (N_EDGES + i)] : e[N_EDGES + i];
}
__device__ __forceinline__ int load_src(const int* e, int f, int i) {
    return f ? e[2 * i] : e[i];
}

// ---------- pass A: coarse bucket histogram (LDS-staged) ----------
__global__ void bucket_hist(const int* __restrict__ eraw, const int* __restrict__ flag,
                            int* __restrict__ bhist) {
    __shared__ int h[NBKT];
    for (int i = threadIdx.x; i < NBKT; i += BLK) h[i] = 0;
    __syncthreads();
    const int f = *flag;
    const int stride = gridDim.x * BLK;
    for (int i = blockIdx.x * BLK + threadIdx.x; i < N_EDGES; i += stride)
        atomicAdd(&h[load_dst(eraw, f, i) >> 7], 1);
    __syncthreads();
    for (int i = threadIdx.x; i < NBKT; i += BLK) {
        const int v = h[i];
        if (v) atomicAdd(&bhist[i], v);
    }
}

// ---------- single-block exclusive scan of bucket counts ----------
__global__ void scan_buckets(const int* __restrict__ bhist, int* __restrict__ base,
                             int* __restrict__ cursor) {
    __shared__ int tmp[1024];
    const int t = threadIdx.x;
    const int v = (t < NBKT) ? bhist[t] : 0;
    tmp[t] = v;
    __syncthreads();
    for (int off = 1; off < 1024; off <<= 1) {
        const int u = (t >= off) ? tmp[t - off] : 0;
        __syncthreads();
        tmp[t] += u;
        __syncthreads();
    }
    if (t < NBKT) {
        const int b = tmp[t] - v;   // exclusive
        base[t] = b;
        cursor[t] = b;
    }
    if (t == 0) base[NBKT] = N_EDGES;
}

// ---------- pass B: block-aggregated scatter into bucket order ----------
__global__ void bucket_scatter(const int* __restrict__ eraw, const int* __restrict__ flag,
                               int* __restrict__ cursor, int* __restrict__ ebkt) {
    __shared__ int h[NBKT];
    const int f = *flag;
    const int e0 = blockIdx.x * EPBLK;
    for (int i = threadIdx.x; i < NBKT; i += BLK) h[i] = 0;
    __syncthreads();
    int bs[EPT], ps[EPT];
#pragma unroll
    for (int k = 0; k < EPT; ++k) {
        const int i = e0 + k * BLK + threadIdx.x;
        if (i < N_EDGES) {
            const int d = load_dst(eraw, f, i);
            const int s = load_src(eraw, f, i);
            bs[k] = d >> 7;
            ps[k] = s | ((d & 127) << PACK_SHIFT);
            atomicAdd(&h[bs[k]], 1);
        } else {
            bs[k] = -1;
            ps[k] = 0;
        }
    }
    __syncthreads();
    for (int b = threadIdx.x; b < NBKT; b += BLK) {
        const int c = h[b];
        if (c) h[b] = atomicAdd(&cursor[b], c);
    }
    __syncthreads();
#pragma unroll
    for (int k = 0; k < EPT; ++k) {
        if (bs[k] >= 0) {
            const int pos = atomicAdd(&h[bs[k]], 1);
            ebkt[pos] = ps[k];
        }
    }
}

// ---------- pass C: per-bucket CSR-ify (dense contiguous writes) ----------
__global__ void csrify(const int* __restrict__ base, const int* __restrict__ ebkt,
                       int* __restrict__ adj, int* __restrict__ rowptr,
                       int* __restrict__ deg) {
    __shared__ int hist[128];
    __shared__ int excl[128];
    __shared__ int lcur[128];
    const int b = blockIdx.x;
    const int s0 = base[b], s1 = base[b + 1];
    for (int i = threadIdx.x; i < 128; i += BLK) hist[i] = 0;
    __syncthreads();
    for (int i = s0 + threadIdx.x; i < s1; i += BLK)
        atomicAdd(&hist[ebkt[i] >> PACK_SHIFT], 1);
    __syncthreads();
    if (threadIdx.x < 128) excl[threadIdx.x] = hist[threadIdx.x];
    __syncthreads();
    for (int off = 1; off < 128; off <<= 1) {
        int t = 0;
        if (threadIdx.x < 128 && threadIdx.x >= off) t = excl[threadIdx.x - off];
        __syncthreads();
        if (threadIdx.x < 128) excl[threadIdx.x] += t;
        __syncthreads();
    }
    if (threadIdx.x < 128) {
        const int e = excl[threadIdx.x] - hist[threadIdx.x];   // exclusive
        lcur[threadIdx.x] = s0 + e;
        const int node = b * 128 + threadIdx.x;
        if (node < N_NODES) {
            rowptr[node] = s0 + e;
            deg[node] = hist[threadIdx.x];
        }
    }
    __syncthreads();
    for (int i = s0 + threadIdx.x; i < s1; i += BLK) {
        const int p = ebkt[i];
        const int pos = atomicAdd(&lcur[p >> PACK_SHIFT], 1);
        adj[pos] = p & ((1 << PACK_SHIFT) - 1);
    }
}

// ---------- helpers ----------
__device__ __forceinline__ void fma_step(float4& acc, float xs, float4 w) {
    acc.x = fmaf(xs, w.x, acc.x);
    acc.y = fmaf(xs, w.y, acc.y);
    acc.z = fmaf(xs, w.z, acc.z);
    acc.w = fmaf(xs, w.w, acc.w);
}

__device__ __forceinline__ void fma_bf(float4& acc, float xs, ushort4 wb) {
    acc.x = fmaf(xs, bf2f(wb.x), acc.x);
    acc.y = fmaf(xs, bf2f(wb.y), acc.y);
    acc.z = fmaf(xs, bf2f(wb.z), acc.z);
    acc.w = fmaf(xs, bf2f(wb.w), acc.w);
}

__device__ __forceinline__ void add4(float4& a, float4 v) {
    a.x += v.x; a.y += v.y; a.z += v.z; a.w += v.w;
}

__device__ __forceinline__ void addbf4(float4& a, ushort4 t) {
    a.x += bf2f(t.x); a.y += bf2f(t.y); a.z += bf2f(t.z); a.w += bf2f(t.w);
}

// ---------- Y[n,C] = X[n,K] @ W[K,C] + b, x LDS-staged; also writes bf16 copy ----------
// launched with exactly n/NPB blocks
template<int K, int C>
__global__ void gemm_bias(const float* __restrict__ X, const float* __restrict__ W,
                          const float* __restrict__ bias, float* __restrict__ Y,
                          unsigned short* __restrict__ Yb, int n) {
    constexpr int CQ = C / 4;       // channel quads
    constexpr int NPB = BLK / CQ;   // nodes per block
    constexpr int KQ = K / 4;       // k quads per row
    __shared__ float4 Ws[K * CQ];
    __shared__ float4 xL[NPB * KQ];   // row r rotated by r quads
    for (int i = threadIdx.x; i < K * CQ; i += BLK)
        Ws[i] = reinterpret_cast<const float4*>(W)[i];
    const int cq = threadIdx.x % CQ;
    const int ns = threadIdx.x / CQ;
    const float4 bv = reinterpret_cast<const float4*>(bias)[cq];
    const float4* X4 = reinterpret_cast<const float4*>(X);
    const int tile = blockIdx.x;
    for (int i = threadIdx.x; i < NPB * KQ; i += BLK) {
        const int r = i / KQ;
        const int k4 = i % KQ;
        xL[r * KQ + ((k4 + r) % KQ)] = X4[(size_t)(tile * NPB + r) * KQ + k4];
    }
    __syncthreads();
    const float4* xr = &xL[ns * KQ];
    float4 acc = bv;
#pragma unroll 4
    for (int k4 = 0; k4 < KQ; ++k4) {
        float4 xv = xr[(k4 + ns) % KQ];
        fma_step(acc, xv.x, Ws[(4 * k4 + 0) * CQ + cq]);
        fma_step(acc, xv.y, Ws[(4 * k4 + 1) * CQ + cq]);
        fma_step(acc, xv.z, Ws[(4 * k4 + 2) * CQ + cq]);
        fma_step(acc, xv.w, Ws[(4 * k4 + 3) * CQ + cq]);
    }
    const size_t oi = (size_t)(tile * NPB + ns) * CQ + cq;
    reinterpret_cast<float4*>(Y)[oi] = acc;
    ushort4 bfv;
    bfv.x = f2bf(acc.x); bfv.y = f2bf(acc.y);
    bfv.z = f2bf(acc.z); bfv.w = f2bf(acc.w);
    reinterpret_cast<ushort4*>(Yb)[oi] = bfv;
}

// ---------- fused gather-aggregate + update: Y = relu(concat(P, agg) @ W + b) ----------
// launched with exactly n/NPB blocks; unroll-8 gather; W in LDS as bf16 (20.5KB total LDS)
template<int KH, int C>
__global__ void update_gather(const float* __restrict__ P,
                              const unsigned short* __restrict__ Pb,
                              const int* __restrict__ rowptr, const int* __restrict__ cnt,
                              const int* __restrict__ adj,
                              const float* __restrict__ W, const float* __restrict__ bias,
                              float* __restrict__ Y, int n) {
    constexpr int CQ = C / 4;
    constexpr int NPB = BLK / CQ;
    constexpr int K = 2 * KH;
    __shared__ ushort4 Wsb[K * CQ];    // bf16 weights: 16KB for K=128,CQ=16
    __shared__ float4 Ag[NPB][CQ];     // 4KB
    for (int i = threadIdx.x; i < K * CQ; i += BLK) {
        const float4 w = reinterpret_cast<const float4*>(W)[i];
        ushort4 wb;
        wb.x = f2bf(w.x); wb.y = f2bf(w.y); wb.z = f2bf(w.z); wb.w = f2bf(w.w);
        Wsb[i] = wb;
    }
    __syncthreads();
    const int cq = threadIdx.x % CQ;
    const int ns = threadIdx.x / CQ;
    const float4 bv = reinterpret_cast<const float4*>(bias)[cq];
    const float4* P4 = reinterpret_cast<const float4*>(P);
    const ushort4* Pb4 = reinterpret_cast<const ushort4*>(Pb);
    const int node = blockIdx.x * NPB + ns;
    const int start = rowptr[node];
    const int deg = cnt[node];
    const float inv = 1.0f / (float)(deg + 1);
    const float4* pr = &P4[(size_t)node * CQ];

    // gather-sum neighbors (bf16 rows), 8 loads in flight
    float4 agg = {0.f, 0.f, 0.f, 0.f};
    int j = 0;
    for (; j + 7 < deg; j += 8) {
        const int s0 = adj[start + j];
        const int s1 = adj[start + j + 1];
        const int s2 = adj[start + j + 2];
        const int s3 = adj[start + j + 3];
        const int s4 = adj[start + j + 4];
        const int s5 = adj[start + j + 5];
        const int s6 = adj[start + j + 6];
        const int s7 = adj[start + j + 7];
        const ushort4 t0 = Pb4[(size_t)s0 * CQ + cq];
        const ushort4 t1 = Pb4[(size_t)s1 * CQ + cq];
        const ushort4 t2 = Pb4[(size_t)s2 * CQ + cq];
        const ushort4 t3 = Pb4[(size_t)s3 * CQ + cq];
        const ushort4 t4 = Pb4[(size_t)s4 * CQ + cq];
        const ushort4 t5 = Pb4[(size_t)s5 * CQ + cq];
        const ushort4 t6 = Pb4[(size_t)s6 * CQ + cq];
        const ushort4 t7 = Pb4[(size_t)s7 * CQ + cq];
        addbf4(agg, t0); addbf4(agg, t1); addbf4(agg, t2); addbf4(agg, t3);
        addbf4(agg, t4); addbf4(agg, t5); addbf4(agg, t6); addbf4(agg, t7);
    }
    if (j + 3 < deg) {
        const int s0 = adj[start + j];
        const int s1 = adj[start + j + 1];
        const int s2 = adj[start + j + 2];
        const int s3 = adj[start + j + 3];
        const ushort4 t0 = Pb4[(size_t)s0 * CQ + cq];
        const ushort4 t1 = Pb4[(size_t)s1 * CQ + cq];
        const ushort4 t2 = Pb4[(size_t)s2 * CQ + cq];
        const ushort4 t3 = Pb4[(size_t)s3 * CQ + cq];
        addbf4(agg, t0); addbf4(agg, t1); addbf4(agg, t2); addbf4(agg, t3);
        j += 4;
    }
    for (; j < deg; ++j)
        addbf4(agg, Pb4[(size_t)adj[start + j] * CQ + cq]);

    float4 acc = bv;
#pragma unroll 4
    for (int k4 = 0; k4 < KH / 4; ++k4) {
        float4 pv = pr[k4];
        fma_bf(acc, pv.x, Wsb[(4 * k4 + 0) * CQ + cq]);
        fma_bf(acc, pv.y, Wsb[(4 * k4 + 1) * CQ + cq]);
        fma_bf(acc, pv.z, Wsb[(4 * k4 + 2) * CQ + cq]);
        fma_bf(acc, pv.w, Wsb[(4 * k4 + 3) * CQ + cq]);
    }
    {
        float4 pv = pr[cq];
        add4(agg, pv);
        agg.x *= inv; agg.y *= inv; agg.z *= inv; agg.w *= inv;
    }
    Ag[ns][cq] = agg;
    __syncthreads();
#pragma unroll 4
    for (int k4 = 0; k4 < KH / 4; ++k4) {
        float4 av = Ag[ns][k4];
        fma_bf(acc, av.x, Wsb[(KH + 4 * k4 + 0) * CQ + cq]);
        fma_bf(acc, av.y, Wsb[(KH + 4 * k4 + 1) * CQ + cq]);
        fma_bf(acc, av.z, Wsb[(KH + 4 * k4 + 2) * CQ + cq]);
        fma_bf(acc, av.w, Wsb[(KH + 4 * k4 + 3) * CQ + cq]);
    }
    acc.x = fmaxf(acc.x, 0.0f);
    acc.y = fmaxf(acc.y, 0.0f);
    acc.z = fmaxf(acc.z, 0.0f);
    acc.w = fmaxf(acc.w, 0.0f);
    reinterpret_cast<float4*>(Y)[(size_t)node * CQ + cq] = acc;
}

// ---------- conv2 update (bf16 gather) fused with final 32->1 linear ----------
// launched with exactly n/8 blocks; unroll-8 gather
__global__ void update2_final(const float* __restrict__ P,
                              const unsigned short* __restrict__ Pb,
                              const int* __restrict__ rowptr, const int* __restrict__ cnt,
                              const int* __restrict__ adj,
                              const float* __restrict__ W, const float* __restrict__ bias,
                              const float* __restrict__ Wl, const float* __restrict__ bl,
                              float* __restrict__ out, int n) {
    __shared__ float Ws[64 * 32];   // 8 KB
    for (int i = threadIdx.x; i < 64 * 32; i += BLK) Ws[i] = W[i];
    __syncthreads();
    const int c = threadIdx.x & 31;
    const int ns = threadIdx.x >> 5;
    const float wl = Wl[c];
    const float bc = bias[c];
    const float blv = bl[0];
    const int node = blockIdx.x * 8 + ns;
    const int start = rowptr[node];
    const int deg = cnt[node];
    const float inv = 1.0f / (float)(deg + 1);
    const float selfp = P[(size_t)node * 32 + c];
    float agg = 0.0f;
    int j = 0;
    for (; j + 7 < deg; j += 8) {
        const int s0 = adj[start + j];
        const int s1 = adj[start + j + 1];
        const int s2 = adj[start + j + 2];
        const int s3 = adj[start + j + 3];
        const int s4 = adj[start + j + 4];
        const int s5 = adj[start + j + 5];
        const int s6 = adj[start + j + 6];
        const int s7 = adj[start + j + 7];
        const float v0 = bf2f(Pb[(size_t)s0 * 32 + c]);
        const float v1 = bf2f(Pb[(size_t)s1 * 32 + c]);
        const float v2 = bf2f(Pb[(size_t)s2 * 32 + c]);
        const float v3 = bf2f(Pb[(size_t)s3 * 32 + c]);
        const float v4 = bf2f(Pb[(size_t)s4 * 32 + c]);
        const float v5 = bf2f(Pb[(size_t)s5 * 32 + c]);
        const float v6 = bf2f(Pb[(size_t)s6 * 32 + c]);
        const float v7 = bf2f(Pb[(size_t)s7 * 32 + c]);
        agg += ((v0 + v1) + (v2 + v3)) + ((v4 + v5) + (v6 + v7));
    }
    if (j + 3 < deg) {
        const int s0 = adj[start + j];
        const int s1 = adj[start + j + 1];
        const int s2 = adj[start + j + 2];
        const int s3 = adj[start + j + 3];
        const float v0 = bf2f(Pb[(size_t)s0 * 32 + c]);
        const float v1 = bf2f(Pb[(size_t)s1 * 32 + c]);
        const float v2 = bf2f(Pb[(size_t)s2 * 32 + c]);
        const float v3 = bf2f(Pb[(size_t)s3 * 32 + c]);
        agg += (v0 + v1) + (v2 + v3);
        j += 4;
    }
    for (; j < deg; ++j) agg += bf2f(Pb[(size_t)adj[start + j] * 32 + c]);
    agg = (agg + selfp) * inv;

    float acc = bc;
#pragma unroll
    for (int k = 0; k < 32; ++k) {
        float pk = __shfl(selfp, k, 32);
        float ak = __shfl(agg,   k, 32);
        acc = fmaf(pk, Ws[k * 32 + c], acc);
        acc = fmaf(ak, Ws[(32 + k) * 32 + c], acc);
    }
    float v = fmaxf(acc, 0.0f) * wl;
#pragma unroll
    for (int off = 16; off >= 1; off >>= 1) v += __shfl_xor(v, off, 32);
    if (c == 0) out[node] = v + blv;
}

extern "C" void kernel_launch(void* const* d_in, const int* in_sizes, int n_in,
                              void* d_out, int out_size, void* d_ws, size_t ws_size,
                              hipStream_t stream) {
    const float* x    = (const float*)d_in[0];
    const int*   eraw = (const int*)d_in[1];
    const float* W2_1 = (const float*)d_in[2];
    const float* b2_1 = (const float*)d_in[3];
    const float* W1_1 = (const float*)d_in[4];
    const float* b1_1 = (const float*)d_in[5];
    const float* W2_2 = (const float*)d_in[6];
    const float* b2_2 = (const float*)d_in[7];
    const float* W1_2 = (const float*)d_in[8];
    const float* b1_2 = (const float*)d_in[9];
    const float* Wl   = (const float*)d_in[10];
    const float* bl   = (const float*)d_in[11];
    float* out = (float*)d_out;

    // workspace layout (~85 MB)
    char* ws = (char*)d_ws;
    int* flag   = (int*)ws;
    size_t off = 256;
    int* bhist  = (int*)(ws + off); off += sizeof(int) * (size_t)(NBKT + 2);
    off = (off + 255) & ~(size_t)255;
    int* base   = (int*)(ws + off); off += sizeof(int) * (size_t)(NBKT + 2);
    off = (off + 255) & ~(size_t)255;
    int* cursor = (int*)(ws + off); off += sizeof(int) * (size_t)(NBKT + 2);
    off = (off + 255) & ~(size_t)255;
    int* ebkt   = (int*)(ws + off); off += sizeof(int) * (size_t)N_EDGES;      // 6.4 MB
    off = (off + 255) & ~(size_t)255;
    int* adj    = (int*)(ws + off); off += sizeof(int) * (size_t)N_EDGES;      // 6.4 MB
    int* rowptr = (int*)(ws + off); off += sizeof(int) * (size_t)N_NODES;
    int* deg    = (int*)(ws + off); off += sizeof(int) * (size_t)N_NODES;
    off = (off + 255) & ~(size_t)255;
    float* bufA = (float*)(ws + off); off += sizeof(float) * (size_t)N_NODES * 64;  // 25.6 MB
    float* bufC = (float*)(ws + off); off += sizeof(float) * (size_t)N_NODES * 64;  // 25.6 MB
    unsigned short* bufAb = (unsigned short*)(ws + off);
    off += sizeof(unsigned short) * (size_t)N_NODES * 64;                           // 12.8 MB

    hipMemsetAsync(bhist, 0, sizeof(int) * (size_t)(NBKT + 2), stream);

    detect_idx64<<<1, 64, 0, stream>>>((const unsigned int*)eraw, flag);
    bucket_hist<<<320, BLK, 0, stream>>>(eraw, flag, bhist);
    scan_buckets<<<1, 1024, 0, stream>>>(bhist, base, cursor);
    bucket_scatter<<<NSCAT, BLK, 0, stream>>>(eraw, flag, cursor, ebkt);
    csrify<<<NBKT, BLK, 0, stream>>>(base, ebkt, adj, rowptr, deg);

    // conv1 (exact grids: one tile per block)
    gemm_bias<128, 64><<<N_NODES / 16, BLK, 0, stream>>>(x, W2_1, b2_1, bufA, bufAb, N_NODES);
    update_gather<64, 64><<<N_NODES / 16, BLK, 0, stream>>>(bufA, bufAb, rowptr, deg, adj, W1_1, b1_1, bufC, N_NODES);

    // conv2 (reuse bufA fp32 + bufAb bf16 for h2pre)
    gemm_bias<64, 32><<<N_NODES / 32, BLK, 0, stream>>>(bufC, W2_2, b2_2, bufA, bufAb, N_NODES);
    update2_final<<<N_NODES / 8, BLK, 0, stream>>>(bufA, bufAb, rowptr, deg, adj, W1_2, b1_2, Wl, bl, out, N_NODES);
}

// Round 11
// 244.529 us; speedup vs baseline: 1.1164x; 1.1164x over previous
//
#include <hip/hip_runtime.h>

#define N_NODES 100000
#define N_EDGES 1600000
constexpr int BLK = 256;
constexpr int NBKT = (N_NODES + 127) / 128;   // 782 buckets of 128 nodes
constexpr int PACK_SHIFT = 17;                // src < 2^17
constexpr int EPT = 16;                       // edges/thread in scatter
constexpr int EPBLK = BLK * EPT;              // 4096
constexpr int NSCAT = (N_EDGES + EPBLK - 1) / EPBLK;   // 391

// ---------- bf16 helpers (RTNE) ----------
__device__ __forceinline__ unsigned short f2bf(float f) {
    unsigned int u = __float_as_uint(f);
    u = (u + 0x7FFFu + ((u >> 16) & 1u)) >> 16;
    return (unsigned short)u;
}
__device__ __forceinline__ float bf2f(unsigned short s) {
    return __uint_as_float(((unsigned int)s) << 16);
}

// ---------- edge dtype detection (int32 vs int64-lowword) ----------
__global__ void detect_idx64(const unsigned int* __restrict__ e, int* __restrict__ flag) {
    if (blockIdx.x == 0 && threadIdx.x == 0) {
        int is64 = 1;
        for (int i = 0; i < 64; ++i) if (e[2 * i + 1] != 0u) { is64 = 0; break; }
        *flag = is64;
    }
}

__device__ __forceinline__ int load_dst(const int* e, int f, int i) {
    return f ? e[2 * (N_EDGES + i)] : e[N_EDGES + i];
}
__device__ __forceinline__ int load_src(const int* e, int f, int i) {
    return f ? e[2 * i] : e[i];
}

// ---------- pass A: coarse bucket histogram (LDS-staged) ----------
__global__ void bucket_hist(const int* __restrict__ eraw, const int* __restrict__ flag,
                            int* __restrict__ bhist) {
    __shared__ int h[NBKT];
    for (int i = threadIdx.x; i < NBKT; i += BLK) h[i] = 0;
    __syncthreads();
    const int f = *flag;
    const int stride = gridDim.x * BLK;
    for (int i = blockIdx.x * BLK + threadIdx.x; i < N_EDGES; i += stride)
        atomicAdd(&h[load_dst(eraw, f, i) >> 7], 1);
    __syncthreads();
    for (int i = threadIdx.x; i < NBKT; i += BLK) {
        const int v = h[i];
        if (v) atomicAdd(&bhist[i], v);
    }
}

// ---------- single-block exclusive scan of bucket counts ----------
__global__ void scan_buckets(const int* __restrict__ bhist, int* __restrict__ base,
                             int* __restrict__ cursor) {
    __shared__ int tmp[1024];
    const int t = threadIdx.x;
    const int v = (t < NBKT) ? bhist[t] : 0;
    tmp[t] = v;
    __syncthreads();
    for (int off = 1; off < 1024; off <<= 1) {
        const int u = (t >= off) ? tmp[t - off] : 0;
        __syncthreads();
        tmp[t] += u;
        __syncthreads();
    }
    if (t < NBKT) {
        const int b = tmp[t] - v;   // exclusive
        base[t] = b;
        cursor[t] = b;
    }
    if (t == 0) base[NBKT] = N_EDGES;
}

// ---------- pass B: block-aggregated scatter into bucket order ----------
__global__ void bucket_scatter(const int* __restrict__ eraw, const int* __restrict__ flag,
                               int* __restrict__ cursor, int* __restrict__ ebkt) {
    __shared__ int h[NBKT];
    const int f = *flag;
    const int e0 = blockIdx.x * EPBLK;
    for (int i = threadIdx.x; i < NBKT; i += BLK) h[i] = 0;
    __syncthreads();
    int bs[EPT], ps[EPT];
#pragma unroll
    for (int k = 0; k < EPT; ++k) {
        const int i = e0 + k * BLK + threadIdx.x;
        if (i < N_EDGES) {
            const int d = load_dst(eraw, f, i);
            const int s = load_src(eraw, f, i);
            bs[k] = d >> 7;
            ps[k] = s | ((d & 127) << PACK_SHIFT);
            atomicAdd(&h[bs[k]], 1);
        } else {
            bs[k] = -1;
            ps[k] = 0;
        }
    }
    __syncthreads();
    for (int b = threadIdx.x; b < NBKT; b += BLK) {
        const int c = h[b];
        if (c) h[b] = atomicAdd(&cursor[b], c);
    }
    __syncthreads();
#pragma unroll
    for (int k = 0; k < EPT; ++k) {
        if (bs[k] >= 0) {
            const int pos = atomicAdd(&h[bs[k]], 1);
            ebkt[pos] = ps[k];
        }
    }
}

// ---------- pass C: per-bucket CSR-ify (dense contiguous writes) ----------
__global__ void csrify(const int* __restrict__ base, const int* __restrict__ ebkt,
                       int* __restrict__ adj, int* __restrict__ rowptr,
                       int* __restrict__ deg) {
    __shared__ int hist[128];
    __shared__ int excl[128];
    __shared__ int lcur[128];
    const int b = blockIdx.x;
    const int s0 = base[b], s1 = base[b + 1];
    for (int i = threadIdx.x; i < 128; i += BLK) hist[i] = 0;
    __syncthreads();
    for (int i = s0 + threadIdx.x; i < s1; i += BLK)
        atomicAdd(&hist[ebkt[i] >> PACK_SHIFT], 1);
    __syncthreads();
    if (threadIdx.x < 128) excl[threadIdx.x] = hist[threadIdx.x];
    __syncthreads();
    for (int off = 1; off < 128; off <<= 1) {
        int t = 0;
        if (threadIdx.x < 128 && threadIdx.x >= off) t = excl[threadIdx.x - off];
        __syncthreads();
        if (threadIdx.x < 128) excl[threadIdx.x] += t;
        __syncthreads();
    }
    if (threadIdx.x < 128) {
        const int e = excl[threadIdx.x] - hist[threadIdx.x];   // exclusive
        lcur[threadIdx.x] = s0 + e;
        const int node = b * 128 + threadIdx.x;
        if (node < N_NODES) {
            rowptr[node] = s0 + e;
            deg[node] = hist[threadIdx.x];
        }
    }
    __syncthreads();
    for (int i = s0 + threadIdx.x; i < s1; i += BLK) {
        const int p = ebkt[i];
        const int pos = atomicAdd(&lcur[p >> PACK_SHIFT], 1);
        adj[pos] = p & ((1 << PACK_SHIFT) - 1);
    }
}

// ---------- helpers ----------
__device__ __forceinline__ void fma_step(float4& acc, float xs, float4 w) {
    acc.x = fmaf(xs, w.x, acc.x);
    acc.y = fmaf(xs, w.y, acc.y);
    acc.z = fmaf(xs, w.z, acc.z);
    acc.w = fmaf(xs, w.w, acc.w);
}

__device__ __forceinline__ void add4(float4& a, float4 v) {
    a.x += v.x; a.y += v.y; a.z += v.z; a.w += v.w;
}

__device__ __forceinline__ void addbf4(float4& a, ushort4 t) {
    a.x += bf2f(t.x); a.y += bf2f(t.y); a.z += bf2f(t.z); a.w += bf2f(t.w);
}

// ---------- Y[n,C] = X[n,K] @ W[K,C] + b, x LDS-staged; also writes bf16 copy ----------
// launched with exactly n/NPB blocks
template<int K, int C>
__global__ void gemm_bias(const float* __restrict__ X, const float* __restrict__ W,
                          const float* __restrict__ bias, float* __restrict__ Y,
                          unsigned short* __restrict__ Yb, int n) {
    constexpr int CQ = C / 4;       // channel quads
    constexpr int NPB = BLK / CQ;   // nodes per block
    constexpr int KQ = K / 4;       // k quads per row
    __shared__ float4 Ws[K * CQ];
    __shared__ float4 xL[NPB * KQ];   // row r rotated by r quads
    for (int i = threadIdx.x; i < K * CQ; i += BLK)
        Ws[i] = reinterpret_cast<const float4*>(W)[i];
    const int cq = threadIdx.x % CQ;
    const int ns = threadIdx.x / CQ;
    const float4 bv = reinterpret_cast<const float4*>(bias)[cq];
    const float4* X4 = reinterpret_cast<const float4*>(X);
    const int tile = blockIdx.x;
    for (int i = threadIdx.x; i < NPB * KQ; i += BLK) {
        const int r = i / KQ;
        const int k4 = i % KQ;
        xL[r * KQ + ((k4 + r) % KQ)] = X4[(size_t)(tile * NPB + r) * KQ + k4];
    }
    __syncthreads();
    const float4* xr = &xL[ns * KQ];
    float4 acc = bv;
#pragma unroll 4
    for (int k4 = 0; k4 < KQ; ++k4) {
        float4 xv = xr[(k4 + ns) % KQ];
        fma_step(acc, xv.x, Ws[(4 * k4 + 0) * CQ + cq]);
        fma_step(acc, xv.y, Ws[(4 * k4 + 1) * CQ + cq]);
        fma_step(acc, xv.z, Ws[(4 * k4 + 2) * CQ + cq]);
        fma_step(acc, xv.w, Ws[(4 * k4 + 3) * CQ + cq]);
    }
    const size_t oi = (size_t)(tile * NPB + ns) * CQ + cq;
    reinterpret_cast<float4*>(Y)[oi] = acc;
    ushort4 bfv;
    bfv.x = f2bf(acc.x); bfv.y = f2bf(acc.y);
    bfv.z = f2bf(acc.z); bfv.w = f2bf(acc.w);
    reinterpret_cast<ushort4*>(Yb)[oi] = bfv;
}

// ---------- fused gather-aggregate + update: Y = relu(concat(P, agg) @ W + b) ----------
// TPB=512, NPB=32: Ws 32KB fp32 + Ag 8KB = 40.9KB -> ~3-4 blocks/CU x 8 waves
// launched with exactly n/NPB blocks; unroll-8 gather
template<int KH, int C, int TPB>
__global__ void update_gather(const float* __restrict__ P,
                              const unsigned short* __restrict__ Pb,
                              const int* __restrict__ rowptr, const int* __restrict__ cnt,
                              const int* __restrict__ adj,
                              const float* __restrict__ W, const float* __restrict__ bias,
                              float* __restrict__ Y, int n) {
    constexpr int CQ = C / 4;
    constexpr int NPB = TPB / CQ;
    constexpr int K = 2 * KH;
    __shared__ float4 Ws[K * CQ];
    __shared__ float4 Ag[NPB][CQ];
    for (int i = threadIdx.x; i < K * CQ; i += TPB)
        Ws[i] = reinterpret_cast<const float4*>(W)[i];
    __syncthreads();
    const int cq = threadIdx.x % CQ;
    const int ns = threadIdx.x / CQ;
    const float4 bv = reinterpret_cast<const float4*>(bias)[cq];
    const float4* P4 = reinterpret_cast<const float4*>(P);
    const ushort4* Pb4 = reinterpret_cast<const ushort4*>(Pb);
    const int node = blockIdx.x * NPB + ns;
    const int start = rowptr[node];
    const int deg = cnt[node];
    const float inv = 1.0f / (float)(deg + 1);
    const float4* pr = &P4[(size_t)node * CQ];

    // gather-sum neighbors (bf16 rows), 8 loads in flight
    float4 agg = {0.f, 0.f, 0.f, 0.f};
    int j = 0;
    for (; j + 7 < deg; j += 8) {
        const int s0 = adj[start + j];
        const int s1 = adj[start + j + 1];
        const int s2 = adj[start + j + 2];
        const int s3 = adj[start + j + 3];
        const int s4 = adj[start + j + 4];
        const int s5 = adj[start + j + 5];
        const int s6 = adj[start + j + 6];
        const int s7 = adj[start + j + 7];
        const ushort4 t0 = Pb4[(size_t)s0 * CQ + cq];
        const ushort4 t1 = Pb4[(size_t)s1 * CQ + cq];
        const ushort4 t2 = Pb4[(size_t)s2 * CQ + cq];
        const ushort4 t3 = Pb4[(size_t)s3 * CQ + cq];
        const ushort4 t4 = Pb4[(size_t)s4 * CQ + cq];
        const ushort4 t5 = Pb4[(size_t)s5 * CQ + cq];
        const ushort4 t6 = Pb4[(size_t)s6 * CQ + cq];
        const ushort4 t7 = Pb4[(size_t)s7 * CQ + cq];
        addbf4(agg, t0); addbf4(agg, t1); addbf4(agg, t2); addbf4(agg, t3);
        addbf4(agg, t4); addbf4(agg, t5); addbf4(agg, t6); addbf4(agg, t7);
    }
    if (j + 3 < deg) {
        const int s0 = adj[start + j];
        const int s1 = adj[start + j + 1];
        const int s2 = adj[start + j + 2];
        const int s3 = adj[start + j + 3];
        const ushort4 t0 = Pb4[(size_t)s0 * CQ + cq];
        const ushort4 t1 = Pb4[(size_t)s1 * CQ + cq];
        const ushort4 t2 = Pb4[(size_t)s2 * CQ + cq];
        const ushort4 t3 = Pb4[(size_t)s3 * CQ + cq];
        addbf4(agg, t0); addbf4(agg, t1); addbf4(agg, t2); addbf4(agg, t3);
        j += 4;
    }
    for (; j < deg; ++j)
        addbf4(agg, Pb4[(size_t)adj[start + j] * CQ + cq]);

    float4 acc = bv;
#pragma unroll 4
    for (int k4 = 0; k4 < KH / 4; ++k4) {
        float4 pv = pr[k4];
        fma_step(acc, pv.x, Ws[(4 * k4 + 0) * CQ + cq]);
        fma_step(acc, pv.y, Ws[(4 * k4 + 1) * CQ + cq]);
        fma_step(acc, pv.z, Ws[(4 * k4 + 2) * CQ + cq]);
        fma_step(acc, pv.w, Ws[(4 * k4 + 3) * CQ + cq]);
    }
    {
        float4 pv = pr[cq];
        add4(agg, pv);
        agg.x *= inv; agg.y *= inv; agg.z *= inv; agg.w *= inv;
    }
    Ag[ns][cq] = agg;
    __syncthreads();
#pragma unroll 4
    for (int k4 = 0; k4 < KH / 4; ++k4) {
        float4 av = Ag[ns][k4];
        fma_step(acc, av.x, Ws[(KH + 4 * k4 + 0) * CQ + cq]);
        fma_step(acc, av.y, Ws[(KH + 4 * k4 + 1) * CQ + cq]);
        fma_step(acc, av.z, Ws[(KH + 4 * k4 + 2) * CQ + cq]);
        fma_step(acc, av.w, Ws[(KH + 4 * k4 + 3) * CQ + cq]);
    }
    acc.x = fmaxf(acc.x, 0.0f);
    acc.y = fmaxf(acc.y, 0.0f);
    acc.z = fmaxf(acc.z, 0.0f);
    acc.w = fmaxf(acc.w, 0.0f);
    reinterpret_cast<float4*>(Y)[(size_t)node * CQ + cq] = acc;
}

// ---------- conv2 update (bf16 gather) fused with final 32->1 linear ----------
// launched with exactly n/8 blocks; unroll-8 gather
__global__ void update2_final(const float* __restrict__ P,
                              const unsigned short* __restrict__ Pb,
                              const int* __restrict__ rowptr, const int* __restrict__ cnt,
                              const int* __restrict__ adj,
                              const float* __restrict__ W, const float* __restrict__ bias,
                              const float* __restrict__ Wl, const float* __restrict__ bl,
                              float* __restrict__ out, int n) {
    __shared__ float Ws[64 * 32];   // 8 KB
    for (int i = threadIdx.x; i < 64 * 32; i += BLK) Ws[i] = W[i];
    __syncthreads();
    const int c = threadIdx.x & 31;
    const int ns = threadIdx.x >> 5;
    const float wl = Wl[c];
    const float bc = bias[c];
    const float blv = bl[0];
    const int node = blockIdx.x * 8 + ns;
    const int start = rowptr[node];
    const int deg = cnt[node];
    const float inv = 1.0f / (float)(deg + 1);
    const float selfp = P[(size_t)node * 32 + c];
    float agg = 0.0f;
    int j = 0;
    for (; j + 7 < deg; j += 8) {
        const int s0 = adj[start + j];
        const int s1 = adj[start + j + 1];
        const int s2 = adj[start + j + 2];
        const int s3 = adj[start + j + 3];
        const int s4 = adj[start + j + 4];
        const int s5 = adj[start + j + 5];
        const int s6 = adj[start + j + 6];
        const int s7 = adj[start + j + 7];
        const float v0 = bf2f(Pb[(size_t)s0 * 32 + c]);
        const float v1 = bf2f(Pb[(size_t)s1 * 32 + c]);
        const float v2 = bf2f(Pb[(size_t)s2 * 32 + c]);
        const float v3 = bf2f(Pb[(size_t)s3 * 32 + c]);
        const float v4 = bf2f(Pb[(size_t)s4 * 32 + c]);
        const float v5 = bf2f(Pb[(size_t)s5 * 32 + c]);
        const float v6 = bf2f(Pb[(size_t)s6 * 32 + c]);
        const float v7 = bf2f(Pb[(size_t)s7 * 32 + c]);
        agg += ((v0 + v1) + (v2 + v3)) + ((v4 + v5) + (v6 + v7));
    }
    if (j + 3 < deg) {
        const int s0 = adj[start + j];
        const int s1 = adj[start + j + 1];
        const int s2 = adj[start + j + 2];
        const int s3 = adj[start + j + 3];
        const float v0 = bf2f(Pb[(size_t)s0 * 32 + c]);
        const float v1 = bf2f(Pb[(size_t)s1 * 32 + c]);
        const float v2 = bf2f(Pb[(size_t)s2 * 32 + c]);
        const float v3 = bf2f(Pb[(size_t)s3 * 32 + c]);
        agg += (v0 + v1) + (v2 + v3);
        j += 4;
    }
    for (; j < deg; ++j) agg += bf2f(Pb[(size_t)adj[start + j] * 32 + c]);
    agg = (agg + selfp) * inv;

    float acc = bc;
#pragma unroll
    for (int k = 0; k < 32; ++k) {
        float pk = __shfl(selfp, k, 32);
        float ak = __shfl(agg,   k, 32);
        acc = fmaf(pk, Ws[k * 32 + c], acc);
        acc = fmaf(ak, Ws[(32 + k) * 32 + c], acc);
    }
    float v = fmaxf(acc, 0.0f) * wl;
#pragma unroll
    for (int off = 16; off >= 1; off >>= 1) v += __shfl_xor(v, off, 32);
    if (c == 0) out[node] = v + blv;
}

extern "C" void kernel_launch(void* const* d_in, const int* in_sizes, int n_in,
                              void* d_out, int out_size, void* d_ws, size_t ws_size,
                              hipStream_t stream) {
    const float* x    = (const float*)d_in[0];
    const int*   eraw = (const int*)d_in[1];
    const float* W2_1 = (const float*)d_in[2];
    const float* b2_1 = (const float*)d_in[3];
    const float* W1_1 = (const float*)d_in[4];
    const float* b1_1 = (const float*)d_in[5];
    const float* W2_2 = (const float*)d_in[6];
    const float* b2_2 = (const float*)d_in[7];
    const float* W1_2 = (const float*)d_in[8];
    const float* b1_2 = (const float*)d_in[9];
    const float* Wl   = (const float*)d_in[10];
    const float* bl   = (const float*)d_in[11];
    float* out = (float*)d_out;

    // workspace layout (~85 MB)
    char* ws = (char*)d_ws;
    int* flag   = (int*)ws;
    size_t off = 256;
    int* bhist  = (int*)(ws + off); off += sizeof(int) * (size_t)(NBKT + 2);
    off = (off + 255) & ~(size_t)255;
    int* base   = (int*)(ws + off); off += sizeof(int) * (size_t)(NBKT + 2);
    off = (off + 255) & ~(size_t)255;
    int* cursor = (int*)(ws + off); off += sizeof(int) * (size_t)(NBKT + 2);
    off = (off + 255) & ~(size_t)255;
    int* ebkt   = (int*)(ws + off); off += sizeof(int) * (size_t)N_EDGES;      // 6.4 MB
    off = (off + 255) & ~(size_t)255;
    int* adj    = (int*)(ws + off); off += sizeof(int) * (size_t)N_EDGES;      // 6.4 MB
    int* rowptr = (int*)(ws + off); off += sizeof(int) * (size_t)N_NODES;
    int* deg    = (int*)(ws + off); off += sizeof(int) * (size_t)N_NODES;
    off = (off + 255) & ~(size_t)255;
    float* bufA = (float*)(ws + off); off += sizeof(float) * (size_t)N_NODES * 64;  // 25.6 MB
    float* bufC = (float*)(ws + off); off += sizeof(float) * (size_t)N_NODES * 64;  // 25.6 MB
    unsigned short* bufAb = (unsigned short*)(ws + off);
    off += sizeof(unsigned short) * (size_t)N_NODES * 64;                           // 12.8 MB

    hipMemsetAsync(bhist, 0, sizeof(int) * (size_t)(NBKT + 2), stream);

    detect_idx64<<<1, 64, 0, stream>>>((const unsigned int*)eraw, flag);
    bucket_hist<<<320, BLK, 0, stream>>>(eraw, flag, bhist);
    scan_buckets<<<1, 1024, 0, stream>>>(bhist, base, cursor);
    bucket_scatter<<<NSCAT, BLK, 0, stream>>>(eraw, flag, cursor, ebkt);
    csrify<<<NBKT, BLK, 0, stream>>>(base, ebkt, adj, rowptr, deg);

    // conv1 (exact grids: one tile per block)
    gemm_bias<128, 64><<<N_NODES / 16, BLK, 0, stream>>>(x, W2_1, b2_1, bufA, bufAb, N_NODES);
    update_gather<64, 64, 512><<<N_NODES / 32, 512, 0, stream>>>(bufA, bufAb, rowptr, deg, adj, W1_1, b1_1, bufC, N_NODES);

    // conv2 (reuse bufA fp32 + bufAb bf16 for h2pre)
    gemm_bias<64, 32><<<N_NODES / 32, BLK, 0, stream>>>(bufC, W2_2, b2_2, bufA, bufAb, N_NODES);
    update2_final<<<N_NODES / 8, BLK, 0, stream>>>(bufA, bufAb, rowptr, deg, adj, W1_2, b1_2, Wl, bl, out, N_NODES);
}

// Round 12
// 201.888 us; speedup vs baseline: 1.3522x; 1.2112x over previous
//
#include <hip/hip_runtime.h>

#define N_NODES 100000
#define N_EDGES 1600000
constexpr int BLK = 256;
constexpr int NBKT = (N_NODES + 127) / 128;   // 782 buckets of 128 nodes
constexpr int PACK_SHIFT = 17;                // src < 2^17
constexpr int EPT = 16;                       // edges/thread in scatter
constexpr int EPBLK = BLK * EPT;              // 4096
constexpr int NSCAT = (N_EDGES + EPBLK - 1) / EPBLK;   // 391

// ---------- bf16 helpers (RTNE) ----------
__device__ __forceinline__ unsigned short f2bf(float f) {
    unsigned int u = __float_as_uint(f);
    u = (u + 0x7FFFu + ((u >> 16) & 1u)) >> 16;
    return (unsigned short)u;
}
__device__ __forceinline__ float bf2f(unsigned short s) {
    return __uint_as_float(((unsigned int)s) << 16);
}

// ---------- edge dtype detection (int32 vs int64-lowword) ----------
__global__ void detect_idx64(const unsigned int* __restrict__ e, int* __restrict__ flag) {
    if (blockIdx.x == 0 && threadIdx.x == 0) {
        int is64 = 1;
        for (int i = 0; i < 64; ++i) if (e[2 * i + 1] != 0u) { is64 = 0; break; }
        *flag = is64;
    }
}

__device__ __forceinline__ int load_dst(const int* e, int f, int i) {
    return f ? e[2 * (N_EDGES + i)] : e[N_EDGES + i];
}
__device__ __forceinline__ int load_src(const int* e, int f, int i) {
    return f ? e[2 * i] : e[i];
}

// ---------- pass A: coarse bucket histogram (LDS-staged) ----------
__global__ void bucket_hist(const int* __restrict__ eraw, const int* __restrict__ flag,
                            int* __restrict__ bhist) {
    __shared__ int h[NBKT];
    for (int i = threadIdx.x; i < NBKT; i += BLK) h[i] = 0;
    __syncthreads();
    const int f = *flag;
    const int stride = gridDim.x * BLK;
    for (int i = blockIdx.x * BLK + threadIdx.x; i < N_EDGES; i += stride)
        atomicAdd(&h[load_dst(eraw, f, i) >> 7], 1);
    __syncthreads();
    for (int i = threadIdx.x; i < NBKT; i += BLK) {
        const int v = h[i];
        if (v) atomicAdd(&bhist[i], v);
    }
}

// ---------- single-block exclusive scan of bucket counts ----------
__global__ void scan_buckets(const int* __restrict__ bhist, int* __restrict__ base,
                             int* __restrict__ cursor) {
    __shared__ int tmp[1024];
    const int t = threadIdx.x;
    const int v = (t < NBKT) ? bhist[t] : 0;
    tmp[t] = v;
    __syncthreads();
    for (int off = 1; off < 1024; off <<= 1) {
        const int u = (t >= off) ? tmp[t - off] : 0;
        __syncthreads();
        tmp[t] += u;
        __syncthreads();
    }
    if (t < NBKT) {
        const int b = tmp[t] - v;   // exclusive
        base[t] = b;
        cursor[t] = b;
    }
    if (t == 0) base[NBKT] = N_EDGES;
}

// ---------- pass B: block-aggregated scatter into bucket order ----------
__global__ void bucket_scatter(const int* __restrict__ eraw, const int* __restrict__ flag,
                               int* __restrict__ cursor, int* __restrict__ ebkt) {
    __shared__ int h[NBKT];
    const int f = *flag;
    const int e0 = blockIdx.x * EPBLK;
    for (int i = threadIdx.x; i < NBKT; i += BLK) h[i] = 0;
    __syncthreads();
    int bs[EPT], ps[EPT];
#pragma unroll
    for (int k = 0; k < EPT; ++k) {
        const int i = e0 + k * BLK + threadIdx.x;
        if (i < N_EDGES) {
            const int d = load_dst(eraw, f, i);
            const int s = load_src(eraw, f, i);
            bs[k] = d >> 7;
            ps[k] = s | ((d & 127) << PACK_SHIFT);
            atomicAdd(&h[bs[k]], 1);
        } else {
            bs[k] = -1;
            ps[k] = 0;
        }
    }
    __syncthreads();
    for (int b = threadIdx.x; b < NBKT; b += BLK) {
        const int c = h[b];
        if (c) h[b] = atomicAdd(&cursor[b], c);
    }
    __syncthreads();
#pragma unroll
    for (int k = 0; k < EPT; ++k) {
        if (bs[k] >= 0) {
            const int pos = atomicAdd(&h[bs[k]], 1);
            ebkt[pos] = ps[k];
        }
    }
}

// ---------- pass C: per-bucket CSR-ify (dense contiguous writes) ----------
__global__ void csrify(const int* __restrict__ base, const int* __restrict__ ebkt,
                       int* __restrict__ adj, int* __restrict__ rowptr,
                       int* __restrict__ deg) {
    __shared__ int hist[128];
    __shared__ int excl[128];
    __shared__ int lcur[128];
    const int b = blockIdx.x;
    const int s0 = base[b], s1 = base[b + 1];
    for (int i = threadIdx.x; i < 128; i += BLK) hist[i] = 0;
    __syncthreads();
    for (int i = s0 + threadIdx.x; i < s1; i += BLK)
        atomicAdd(&hist[ebkt[i] >> PACK_SHIFT], 1);
    __syncthreads();
    if (threadIdx.x < 128) excl[threadIdx.x] = hist[threadIdx.x];
    __syncthreads();
    for (int off = 1; off < 128; off <<= 1) {
        int t = 0;
        if (threadIdx.x < 128 && threadIdx.x >= off) t = excl[threadIdx.x - off];
        __syncthreads();
        if (threadIdx.x < 128) excl[threadIdx.x] += t;
        __syncthreads();
    }
    if (threadIdx.x < 128) {
        const int e = excl[threadIdx.x] - hist[threadIdx.x];   // exclusive
        lcur[threadIdx.x] = s0 + e;
        const int node = b * 128 + threadIdx.x;
        if (node < N_NODES) {
            rowptr[node] = s0 + e;
            deg[node] = hist[threadIdx.x];
        }
    }
    __syncthreads();
    for (int i = s0 + threadIdx.x; i < s1; i += BLK) {
        const int p = ebkt[i];
        const int pos = atomicAdd(&lcur[p >> PACK_SHIFT], 1);
        adj[pos] = p & ((1 << PACK_SHIFT) - 1);
    }
}

// ---------- helpers ----------
__device__ __forceinline__ void fma_step(float4& acc, float xs, float4 w) {
    acc.x = fmaf(xs, w.x, acc.x);
    acc.y = fmaf(xs, w.y, acc.y);
    acc.z = fmaf(xs, w.z, acc.z);
    acc.w = fmaf(xs, w.w, acc.w);
}

__device__ __forceinline__ void add4(float4& a, float4 v) {
    a.x += v.x; a.y += v.y; a.z += v.z; a.w += v.w;
}

__device__ __forceinline__ void addbf4(float4& a, ushort4 t) {
    a.x += bf2f(t.x); a.y += bf2f(t.y); a.z += bf2f(t.z); a.w += bf2f(t.w);
}

// ---------- Y[n,C] = X[n,K] @ W[K,C] + b, x LDS-staged; also writes bf16 copy ----------
// launched with exactly n/NPB blocks
template<int K, int C>
__global__ void gemm_bias(const float* __restrict__ X, const float* __restrict__ W,
                          const float* __restrict__ bias, float* __restrict__ Y,
                          unsigned short* __restrict__ Yb, int n) {
    constexpr int CQ = C / 4;       // channel quads
    constexpr int NPB = BLK / CQ;   // nodes per block
    constexpr int KQ = K / 4;       // k quads per row
    __shared__ float4 Ws[K * CQ];
    __shared__ float4 xL[NPB * KQ];   // row r rotated by r quads
    for (int i = threadIdx.x; i < K * CQ; i += BLK)
        Ws[i] = reinterpret_cast<const float4*>(W)[i];
    const int cq = threadIdx.x % CQ;
    const int ns = threadIdx.x / CQ;
    const float4 bv = reinterpret_cast<const float4*>(bias)[cq];
    const float4* X4 = reinterpret_cast<const float4*>(X);
    const int tile = blockIdx.x;
    for (int i = threadIdx.x; i < NPB * KQ; i += BLK) {
        const int r = i / KQ;
        const int k4 = i % KQ;
        xL[r * KQ + ((k4 + r) % KQ)] = X4[(size_t)(tile * NPB + r) * KQ + k4];
    }
    __syncthreads();
    const float4* xr = &xL[ns * KQ];
    float4 acc = bv;
#pragma unroll 4
    for (int k4 = 0; k4 < KQ; ++k4) {
        float4 xv = xr[(k4 + ns) % KQ];
        fma_step(acc, xv.x, Ws[(4 * k4 + 0) * CQ + cq]);
        fma_step(acc, xv.y, Ws[(4 * k4 + 1) * CQ + cq]);
        fma_step(acc, xv.z, Ws[(4 * k4 + 2) * CQ + cq]);
        fma_step(acc, xv.w, Ws[(4 * k4 + 3) * CQ + cq]);
    }
    const size_t oi = (size_t)(tile * NPB + ns) * CQ + cq;
    reinterpret_cast<float4*>(Y)[oi] = acc;
    ushort4 bfv;
    bfv.x = f2bf(acc.x); bfv.y = f2bf(acc.y);
    bfv.z = f2bf(acc.z); bfv.w = f2bf(acc.w);
    reinterpret_cast<ushort4*>(Yb)[oi] = bfv;
}

// ---------- fused gather-aggregate + update: Y = relu(concat(P, agg) @ W + b) ----------
// TPB=512, NPB=32: Ws 32KB fp32 + Ag 8KB -> ~3 blocks/CU x 8 waves
// launched with exactly n/NPB blocks; unroll-8 gather
template<int KH, int C, int TPB>
__global__ void update_gather(const float* __restrict__ P,
                              const unsigned short* __restrict__ Pb,
                              const int* __restrict__ rowptr, const int* __restrict__ cnt,
                              const int* __restrict__ adj,
                              const float* __restrict__ W, const float* __restrict__ bias,
                              float* __restrict__ Y, int n) {
    constexpr int CQ = C / 4;
    constexpr int NPB = TPB / CQ;
    constexpr int K = 2 * KH;
    __shared__ float4 Ws[K * CQ];
    __shared__ float4 Ag[NPB][CQ];
    for (int i = threadIdx.x; i < K * CQ; i += TPB)
        Ws[i] = reinterpret_cast<const float4*>(W)[i];
    __syncthreads();
    const int cq = threadIdx.x % CQ;
    const int ns = threadIdx.x / CQ;
    const float4 bv = reinterpret_cast<const float4*>(bias)[cq];
    const float4* P4 = reinterpret_cast<const float4*>(P);
    const ushort4* Pb4 = reinterpret_cast<const ushort4*>(Pb);
    const int node = blockIdx.x * NPB + ns;
    const int start = rowptr[node];
    const int deg = cnt[node];
    const float inv = 1.0f / (float)(deg + 1);
    const float4* pr = &P4[(size_t)node * CQ];

    // gather-sum neighbors (bf16 rows), 8 loads in flight
    float4 agg = {0.f, 0.f, 0.f, 0.f};
    int j = 0;
    for (; j + 7 < deg; j += 8) {
        const int s0 = adj[start + j];
        const int s1 = adj[start + j + 1];
        const int s2 = adj[start + j + 2];
        const int s3 = adj[start + j + 3];
        const int s4 = adj[start + j + 4];
        const int s5 = adj[start + j + 5];
        const int s6 = adj[start + j + 6];
        const int s7 = adj[start + j + 7];
        const ushort4 t0 = Pb4[(size_t)s0 * CQ + cq];
        const ushort4 t1 = Pb4[(size_t)s1 * CQ + cq];
        const ushort4 t2 = Pb4[(size_t)s2 * CQ + cq];
        const ushort4 t3 = Pb4[(size_t)s3 * CQ + cq];
        const ushort4 t4 = Pb4[(size_t)s4 * CQ + cq];
        const ushort4 t5 = Pb4[(size_t)s5 * CQ + cq];
        const ushort4 t6 = Pb4[(size_t)s6 * CQ + cq];
        const ushort4 t7 = Pb4[(size_t)s7 * CQ + cq];
        addbf4(agg, t0); addbf4(agg, t1); addbf4(agg, t2); addbf4(agg, t3);
        addbf4(agg, t4); addbf4(agg, t5); addbf4(agg, t6); addbf4(agg, t7);
    }
    if (j + 3 < deg) {
        const int s0 = adj[start + j];
        const int s1 = adj[start + j + 1];
        const int s2 = adj[start + j + 2];
        const int s3 = adj[start + j + 3];
        const ushort4 t0 = Pb4[(size_t)s0 * CQ + cq];
        const ushort4 t1 = Pb4[(size_t)s1 * CQ + cq];
        const ushort4 t2 = Pb4[(size_t)s2 * CQ + cq];
        const ushort4 t3 = Pb4[(size_t)s3 * CQ + cq];
        addbf4(agg, t0); addbf4(agg, t1); addbf4(agg, t2); addbf4(agg, t3);
        j += 4;
    }
    for (; j < deg; ++j)
        addbf4(agg, Pb4[(size_t)adj[start + j] * CQ + cq]);

    float4 acc = bv;
#pragma unroll 4
    for (int k4 = 0; k4 < KH / 4; ++k4) {
        float4 pv = pr[k4];
        fma_step(acc, pv.x, Ws[(4 * k4 + 0) * CQ + cq]);
        fma_step(acc, pv.y, Ws[(4 * k4 + 1) * CQ + cq]);
        fma_step(acc, pv.z, Ws[(4 * k4 + 2) * CQ + cq]);
        fma_step(acc, pv.w, Ws[(4 * k4 + 3) * CQ + cq]);
    }
    {
        float4 pv = pr[cq];
        add4(agg, pv);
        agg.x *= inv; agg.y *= inv; agg.z *= inv; agg.w *= inv;
    }
    Ag[ns][cq] = agg;
    __syncthreads();
#pragma unroll 4
    for (int k4 = 0; k4 < KH / 4; ++k4) {
        float4 av = Ag[ns][k4];
        fma_step(acc, av.x, Ws[(KH + 4 * k4 + 0) * CQ + cq]);
        fma_step(acc, av.y, Ws[(KH + 4 * k4 + 1) * CQ + cq]);
        fma_step(acc, av.z, Ws[(KH + 4 * k4 + 2) * CQ + cq]);
        fma_step(acc, av.w, Ws[(KH + 4 * k4 + 3) * CQ + cq]);
    }
    acc.x = fmaxf(acc.x, 0.0f);
    acc.y = fmaxf(acc.y, 0.0f);
    acc.z = fmaxf(acc.z, 0.0f);
    acc.w = fmaxf(acc.w, 0.0f);
    reinterpret_cast<float4*>(Y)[(size_t)node * CQ + cq] = acc;
}

// ---------- conv2 update (bf16 ushort4 gather) fused with final 32->1 linear ----------
// update_gather structure: CQ=8 lanes/node (float4 out channels), NPB=32 nodes/block.
// launched with exactly n/32 blocks
__global__ void update2_final(const float* __restrict__ P,
                              const unsigned short* __restrict__ Pb,
                              const int* __restrict__ rowptr, const int* __restrict__ cnt,
                              const int* __restrict__ adj,
                              const float* __restrict__ W, const float* __restrict__ bias,
                              const float* __restrict__ Wl, const float* __restrict__ bl,
                              float* __restrict__ out, int n) {
    constexpr int CQ = 8;           // 32 channels / 4
    constexpr int NPB = BLK / CQ;   // 32 nodes per block
    __shared__ float4 Ws[64 * CQ];  // 8 KB: W[64][32] as quads
    __shared__ float4 Ag[NPB][CQ];  // 4 KB
    for (int i = threadIdx.x; i < 64 * CQ; i += BLK)
        Ws[i] = reinterpret_cast<const float4*>(W)[i];
    __syncthreads();
    const int cq = threadIdx.x % CQ;
    const int ns = threadIdx.x / CQ;
    const float4 bv = reinterpret_cast<const float4*>(bias)[cq];
    const float4 wlv = reinterpret_cast<const float4*>(Wl)[cq];
    const float blv = bl[0];
    const float4* P4 = reinterpret_cast<const float4*>(P);
    const ushort4* Pb4 = reinterpret_cast<const ushort4*>(Pb);
    const int node = blockIdx.x * NPB + ns;
    const int start = rowptr[node];
    const int deg = cnt[node];
    const float inv = 1.0f / (float)(deg + 1);
    const float4* pr = &P4[(size_t)node * CQ];

    // gather-sum neighbors (bf16 rows), 8 loads in flight
    float4 agg = {0.f, 0.f, 0.f, 0.f};
    int j = 0;
    for (; j + 7 < deg; j += 8) {
        const int s0 = adj[start + j];
        const int s1 = adj[start + j + 1];
        const int s2 = adj[start + j + 2];
        const int s3 = adj[start + j + 3];
        const int s4 = adj[start + j + 4];
        const int s5 = adj[start + j + 5];
        const int s6 = adj[start + j + 6];
        const int s7 = adj[start + j + 7];
        const ushort4 t0 = Pb4[(size_t)s0 * CQ + cq];
        const ushort4 t1 = Pb4[(size_t)s1 * CQ + cq];
        const ushort4 t2 = Pb4[(size_t)s2 * CQ + cq];
        const ushort4 t3 = Pb4[(size_t)s3 * CQ + cq];
        const ushort4 t4 = Pb4[(size_t)s4 * CQ + cq];
        const ushort4 t5 = Pb4[(size_t)s5 * CQ + cq];
        const ushort4 t6 = Pb4[(size_t)s6 * CQ + cq];
        const ushort4 t7 = Pb4[(size_t)s7 * CQ + cq];
        addbf4(agg, t0); addbf4(agg, t1); addbf4(agg, t2); addbf4(agg, t3);
        addbf4(agg, t4); addbf4(agg, t5); addbf4(agg, t6); addbf4(agg, t7);
    }
    if (j + 3 < deg) {
        const int s0 = adj[start + j];
        const int s1 = adj[start + j + 1];
        const int s2 = adj[start + j + 2];
        const int s3 = adj[start + j + 3];
        const ushort4 t0 = Pb4[(size_t)s0 * CQ + cq];
        const ushort4 t1 = Pb4[(size_t)s1 * CQ + cq];
        const ushort4 t2 = Pb4[(size_t)s2 * CQ + cq];
        const ushort4 t3 = Pb4[(size_t)s3 * CQ + cq];
        addbf4(agg, t0); addbf4(agg, t1); addbf4(agg, t2); addbf4(agg, t3);
        j += 4;
    }
    for (; j < deg; ++j)
        addbf4(agg, Pb4[(size_t)adj[start + j] * CQ + cq]);

    float4 acc = bv;
#pragma unroll
    for (int k4 = 0; k4 < 8; ++k4) {
        float4 pv = pr[k4];
        fma_step(acc, pv.x, Ws[(4 * k4 + 0) * CQ + cq]);
        fma_step(acc, pv.y, Ws[(4 * k4 + 1) * CQ + cq]);
        fma_step(acc, pv.z, Ws[(4 * k4 + 2) * CQ + cq]);
        fma_step(acc, pv.w, Ws[(4 * k4 + 3) * CQ + cq]);
    }
    {
        float4 pv = pr[cq];
        add4(agg, pv);
        agg.x *= inv; agg.y *= inv; agg.z *= inv; agg.w *= inv;
    }
    Ag[ns][cq] = agg;
    __syncthreads();
#pragma unroll
    for (int k4 = 0; k4 < 8; ++k4) {
        float4 av = Ag[ns][k4];
        fma_step(acc, av.x, Ws[(32 + 4 * k4 + 0) * CQ + cq]);
        fma_step(acc, av.y, Ws[(32 + 4 * k4 + 1) * CQ + cq]);
        fma_step(acc, av.z, Ws[(32 + 4 * k4 + 2) * CQ + cq]);
        fma_step(acc, av.w, Ws[(32 + 4 * k4 + 3) * CQ + cq]);
    }
    // final linear: v = sum_c relu(acc_c) * Wl_c  over this lane's 4 channels,
    // then reduce across the 8 lanes of the node group
    float v = fmaxf(acc.x, 0.0f) * wlv.x + fmaxf(acc.y, 0.0f) * wlv.y
            + fmaxf(acc.z, 0.0f) * wlv.z + fmaxf(acc.w, 0.0f) * wlv.w;
    v += __shfl_xor(v, 4, 8);
    v += __shfl_xor(v, 2, 8);
    v += __shfl_xor(v, 1, 8);
    if (cq == 0) out[node] = v + blv;
}

extern "C" void kernel_launch(void* const* d_in, const int* in_sizes, int n_in,
                              void* d_out, int out_size, void* d_ws, size_t ws_size,
                              hipStream_t stream) {
    const float* x    = (const float*)d_in[0];
    const int*   eraw = (const int*)d_in[1];
    const float* W2_1 = (const float*)d_in[2];
    const float* b2_1 = (const float*)d_in[3];
    const float* W1_1 = (const float*)d_in[4];
    const float* b1_1 = (const float*)d_in[5];
    const float* W2_2 = (const float*)d_in[6];
    const float* b2_2 = (const float*)d_in[7];
    const float* W1_2 = (const float*)d_in[8];
    const float* b1_2 = (const float*)d_in[9];
    const float* Wl   = (const float*)d_in[10];
    const float* bl   = (const float*)d_in[11];
    float* out = (float*)d_out;

    // workspace layout (~85 MB)
    char* ws = (char*)d_ws;
    int* flag   = (int*)ws;
    size_t off = 256;
    int* bhist  = (int*)(ws + off); off += sizeof(int) * (size_t)(NBKT + 2);
    off = (off + 255) & ~(size_t)255;
    int* base   = (int*)(ws + off); off += sizeof(int) * (size_t)(NBKT + 2);
    off = (off + 255) & ~(size_t)255;
    int* cursor = (int*)(ws + off); off += sizeof(int) * (size_t)(NBKT + 2);
    off = (off + 255) & ~(size_t)255;
    int* ebkt   = (int*)(ws + off); off += sizeof(int) * (size_t)N_EDGES;      // 6.4 MB
    off = (off + 255) & ~(size_t)255;
    int* adj    = (int*)(ws + off); off += sizeof(int) * (size_t)N_EDGES;      // 6.4 MB
    int* rowptr = (int*)(ws + off); off += sizeof(int) * (size_t)N_NODES;
    int* deg    = (int*)(ws + off); off += sizeof(int) * (size_t)N_NODES;
    off = (off + 255) & ~(size_t)255;
    float* bufA = (float*)(ws + off); off += sizeof(float) * (size_t)N_NODES * 64;  // 25.6 MB
    float* bufC = (float*)(ws + off); off += sizeof(float) * (size_t)N_NODES * 64;  // 25.6 MB
    unsigned short* bufAb = (unsigned short*)(ws + off);
    off += sizeof(unsigned short) * (size_t)N_NODES * 64;                           // 12.8 MB

    hipMemsetAsync(bhist, 0, sizeof(int) * (size_t)(NBKT + 2), stream);

    detect_idx64<<<1, 64, 0, stream>>>((const unsigned int*)eraw, flag);
    bucket_hist<<<320, BLK, 0, stream>>>(eraw, flag, bhist);
    scan_buckets<<<1, 1024, 0, stream>>>(bhist, base, cursor);
    bucket_scatter<<<NSCAT, BLK, 0, stream>>>(eraw, flag, cursor, ebkt);
    csrify<<<NBKT, BLK, 0, stream>>>(base, ebkt, adj, rowptr, deg);

    // conv1 (exact grids: one tile per block)
    gemm_bias<128, 64><<<N_NODES / 16, BLK, 0, stream>>>(x, W2_1, b2_1, bufA, bufAb, N_NODES);
    update_gather<64, 64, 512><<<N_NODES / 32, 512, 0, stream>>>(bufA, bufAb, rowptr, deg, adj, W1_1, b1_1, bufC, N_NODES);

    // conv2 (reuse bufA fp32 + bufAb bf16 for h2pre)
    gemm_bias<64, 32><<<N_NODES / 32, BLK, 0, stream>>>(bufC, W2_2, b2_2, bufA, bufAb, N_NODES);
    update2_final<<<N_NODES / 32, BLK, 0, stream>>>(bufA, bufAb, rowptr, deg, adj, W1_2, b1_2, Wl, bl, out, N_NODES);
}